// Round 1
// baseline (7176.741 us; speedup 1.0000x reference)
//
#include <hip/hip_runtime.h>
#include <hip/hip_bf16.h>
#include <cstdint>

// Problem constants
#define EMBED   192
#define DINNER  384
#define DSTATE  4
#define DCONV   4
#define DTRANK  12
#define NMIX    2
#define RANK    4
#define BB      8
#define LL      4096            // H*W = 64*64
#define NBL     (BB*LL)         // 32768 rows

// ---------------------------------------------------------------------------
// Transpose (B, C, L) -> (B, L, C)
// ---------------------------------------------------------------------------
__global__ __launch_bounds__(256) void k_transpose(const float* __restrict__ x,
                                                   float* __restrict__ h0) {
    __shared__ float tile[32][33];
    int b  = blockIdx.z;
    int c0 = blockIdx.y * 32;
    int l0 = blockIdx.x * 32;
    int tx = threadIdx.x;       // 0..31
    int ty = threadIdx.y;       // 0..7
    #pragma unroll
    for (int i = 0; i < 4; i++) {
        int c = c0 + ty + i * 8;
        tile[ty + i * 8][tx] = x[((size_t)b * EMBED + c) * LL + l0 + tx];
    }
    __syncthreads();
    #pragma unroll
    for (int i = 0; i < 4; i++) {
        int l = l0 + ty + i * 8;
        h0[((size_t)b * LL + l) * EMBED + c0 + tx] = tile[tx][ty + i * 8];
    }
}

// ---------------------------------------------------------------------------
// Tiled SGEMM, "NT": C[m,n] = sum_k A[m*lda+k] * B[n*ldb+k]
// Requires M%64==0, N%64==0, K%16==0 (true for all call sites).
// ---------------------------------------------------------------------------
__global__ __launch_bounds__(256) void k_gemm_nt(const float* __restrict__ A, int lda,
                                                 const float* __restrict__ Bw, int ldb,
                                                 float* __restrict__ C, int ldc,
                                                 int M, int N, int K) {
    __shared__ float As[16][65];
    __shared__ float Bs[16][65];
    int tid = threadIdx.x;
    int m0 = blockIdx.y * 64;
    int n0 = blockIdx.x * 64;
    int tm = (tid >> 4) * 4;
    int tn = (tid & 15) * 4;
    float acc[4][4] = {};
    for (int k0 = 0; k0 < K; k0 += 16) {
        #pragma unroll
        for (int i = 0; i < 4; i++) {
            int idx = tid + i * 256;
            int r = idx >> 4;
            int c = idx & 15;
            As[c][r] = A[(size_t)(m0 + r) * lda + k0 + c];
            Bs[c][r] = Bw[(size_t)(n0 + r) * ldb + k0 + c];
        }
        __syncthreads();
        #pragma unroll
        for (int kk = 0; kk < 16; kk++) {
            float a[4], b[4];
            #pragma unroll
            for (int i = 0; i < 4; i++) a[i] = As[kk][tm + i];
            #pragma unroll
            for (int j = 0; j < 4; j++) b[j] = Bs[kk][tn + j];
            #pragma unroll
            for (int i = 0; i < 4; i++)
                #pragma unroll
                for (int j = 0; j < 4; j++)
                    acc[i][j] += a[i] * b[j];
        }
        __syncthreads();
    }
    #pragma unroll
    for (int i = 0; i < 4; i++)
        #pragma unroll
        for (int j = 0; j < 4; j++)
            C[(size_t)(m0 + tm + i) * ldc + n0 + tn + j] = acc[i][j];
}

// ---------------------------------------------------------------------------
// Depthwise causal conv (width 4) + bias + SiLU.
// Reads xin = xz[:, :, 0:384]; writes xa (B,L,384).
// ---------------------------------------------------------------------------
__global__ __launch_bounds__(256) void k_conv_silu(const float* __restrict__ xz,
                                                   const float* __restrict__ cw,
                                                   const float* __restrict__ cb,
                                                   float* __restrict__ xa) {
    int gid = blockIdx.x * 256 + threadIdx.x;           // over NBL*384
    int d  = gid % DINNER;
    int bl = gid / DINNER;
    int l  = bl & (LL - 1);
    int b  = bl >> 12;
    float acc = cb[d];
    #pragma unroll
    for (int k = 0; k < DCONV; k++) {
        int ls = l - 3 + k;
        if (ls >= 0)
            acc += cw[d * DCONV + k] * xz[((size_t)(b * LL + ls)) * 768 + d];
    }
    float sg = 1.f / (1.f + __expf(-acc));
    xa[gid] = acc * sg;
}

// ---------------------------------------------------------------------------
// x_proj: x_dbl[m,e] = sum_k xa[m,k] * xpw[e,k], e in 0..19
// block: 256 threads = 8 rows x 32 lanes (lanes 20..31 idle)
// ---------------------------------------------------------------------------
__global__ __launch_bounds__(256) void k_xproj(const float* __restrict__ xa,
                                               const float* __restrict__ xpw,
                                               float* __restrict__ xdbl) {
    int tid = threadIdx.x;
    int e  = tid & 31;
    int mo = tid >> 5;
    int m  = blockIdx.x * 8 + mo;
    if (e >= 20) return;
    const float* a = xa + (size_t)m * DINNER;
    const float* w = xpw + e * DINNER;
    float s = 0.f;
    for (int k = 0; k < DINNER; k++) s += a[k] * w[k];
    xdbl[m * 20 + e] = s;
}

// ---------------------------------------------------------------------------
// dt_proj + softplus: dt[m,n] = softplus(sum_r xdbl[m,r]*dtw[n,r] + dtb[n])
// ---------------------------------------------------------------------------
__global__ __launch_bounds__(256) void k_dtproj(const float* __restrict__ xdbl,
                                                const float* __restrict__ dtw,
                                                const float* __restrict__ dtb,
                                                float* __restrict__ dt) {
    int gid = blockIdx.x * 256 + threadIdx.x;           // over NBL*384
    int n = gid % DINNER;
    int m = gid / DINNER;
    const float* a = xdbl + m * 20;
    const float* w = dtw + n * DTRANK;
    float s = dtb[n];
    #pragma unroll
    for (int r = 0; r < DTRANK; r++) s += a[r] * w[r];
    // stable softplus
    float sp = fmaxf(s, 0.f) + log1pf(__expf(-fabsf(s)));
    dt[gid] = sp;
}

// ---------------------------------------------------------------------------
// Selective scan, state-parallel (4 lanes per (b,d) chain).
// y (with +xa*D and *silu(z) fused) written into xz cols 0..383 (dead xin).
// ---------------------------------------------------------------------------
__global__ __launch_bounds__(256) void k_scan(const float* __restrict__ dt,
                                              const float* __restrict__ xa,
                                              const float* __restrict__ xz,
                                              const float* __restrict__ xdbl,
                                              const float* __restrict__ A_log,
                                              const float* __restrict__ Dp,
                                              float* __restrict__ y) {
    int gid   = blockIdx.x * 256 + threadIdx.x;   // 0 .. 3072*4-1
    int s     = gid & 3;
    int chain = gid >> 2;
    int d = chain % DINNER;
    int b = chain / DINNER;
    float As = -__expf(A_log[d * DSTATE + s]);
    float Dd = Dp[d];
    const float* dtp = dt   + (size_t)b * LL * DINNER + d;
    const float* xap = xa   + (size_t)b * LL * DINNER + d;
    const float* zp  = xz   + (size_t)b * LL * 768 + DINNER + d;
    const float* bcp = xdbl + (size_t)b * LL * 20;
    float*       yp  = y    + (size_t)b * LL * 768 + d;
    float h = 0.f;
    for (int l = 0; l < LL; l++) {
        float dtv = dtp[(size_t)l * DINNER];
        float xav = xap[(size_t)l * DINNER];
        float Bv = bcp[l * 20 + DTRANK + s];
        float Cv = bcp[l * 20 + DTRANK + DSTATE + s];
        h = __expf(dtv * As) * h + dtv * Bv * xav;
        float ys = h * Cv;
        ys += __shfl_xor(ys, 1);
        ys += __shfl_xor(ys, 2);
        if (s == 0) {
            float zv = zp[(size_t)l * 768];
            float yv = ys + xav * Dd;
            yv *= zv * (1.f / (1.f + __expf(-zv)));
            yp[(size_t)l * 768] = yv;
        }
    }
}

// ---------------------------------------------------------------------------
// Low-rank (U then V) + residual + LayerNorm over C, write (B,C,L).
// One wave per (b,l); lane holds c = lane, lane+64, lane+128.
// ---------------------------------------------------------------------------
__global__ __launch_bounds__(256) void k_lowrank_ln(const float* __restrict__ h2,
                                                    const float* __restrict__ h0,
                                                    const float* __restrict__ U,
                                                    const float* __restrict__ V,
                                                    const float* __restrict__ g,
                                                    const float* __restrict__ be,
                                                    float* __restrict__ out) {
    int wid  = threadIdx.x >> 6;
    int lane = threadIdx.x & 63;
    int m = blockIdx.x * 4 + wid;       // 0..NBL-1
    int b = m >> 12;
    int l = m & (LL - 1);
    const float* hr  = h2 + (size_t)m * EMBED;
    const float* h0r = h0 + (size_t)m * EMBED;
    float hv[3];
    #pragma unroll
    for (int i = 0; i < 3; i++) hv[i] = hr[lane + 64 * i];
    float r[RANK];
    #pragma unroll
    for (int j = 0; j < RANK; j++) {
        float p = 0.f;
        #pragma unroll
        for (int i = 0; i < 3; i++) p += hv[i] * U[j * EMBED + lane + 64 * i];
        #pragma unroll
        for (int off = 1; off < 64; off <<= 1) p += __shfl_xor(p, off);
        r[j] = p;
    }
    float u[3], s1 = 0.f, s2 = 0.f;
    #pragma unroll
    for (int i = 0; i < 3; i++) {
        int c = lane + 64 * i;
        float v = r[0] * V[c * 4 + 0] + r[1] * V[c * 4 + 1]
                + r[2] * V[c * 4 + 2] + r[3] * V[c * 4 + 3];
        u[i] = v + h0r[c];
        s1 += u[i];
        s2 += u[i] * u[i];
    }
    #pragma unroll
    for (int off = 1; off < 64; off <<= 1) {
        s1 += __shfl_xor(s1, off);
        s2 += __shfl_xor(s2, off);
    }
    float mean = s1 * (1.f / EMBED);
    float var  = s2 * (1.f / EMBED) - mean * mean;
    float inv  = rsqrtf(var + 1e-5f);
    #pragma unroll
    for (int i = 0; i < 3; i++) {
        int c = lane + 64 * i;
        out[((size_t)(b * EMBED + c)) * LL + l] = (u[i] - mean) * inv * g[c] + be[c];
    }
}

// ---------------------------------------------------------------------------
extern "C" void kernel_launch(void* const* d_in, const int* in_sizes, int n_in,
                              void* d_out, int out_size, void* d_ws, size_t ws_size,
                              hipStream_t stream) {
    const float* x          = (const float*)d_in[0];
    const float* in_proj_w  = (const float*)d_in[1];
    const float* conv_w     = (const float*)d_in[2];
    const float* conv_b     = (const float*)d_in[3];
    const float* x_proj_w   = (const float*)d_in[4];
    const float* dt_proj_w  = (const float*)d_in[5];
    const float* dt_proj_b  = (const float*)d_in[6];
    const float* A_log      = (const float*)d_in[7];
    const float* Dp         = (const float*)d_in[8];
    const float* out_proj_w = (const float*)d_in[9];
    const float* U_w        = (const float*)d_in[10];
    const float* V_w        = (const float*)d_in[11];
    const float* ln_g       = (const float*)d_in[12];
    const float* ln_b       = (const float*)d_in[13];
    float* out = (float*)d_out;

    // Workspace layout (floats). Total = 63,700,992 floats = 243 MiB.
    float* ws   = (float*)d_ws;
    float* h0   = ws;                      // NBL*192
    float* h1   = h0  + (size_t)NBL * EMBED;
    float* xzb  = h1  + (size_t)NBL * EMBED;   // NBL*768
    float* xab  = xzb + (size_t)NBL * 768;     // NBL*384
    float* xdb  = xab + (size_t)NBL * DINNER;  // NBL*20
    float* dtbf = xdb + (size_t)NBL * 20;      // NBL*384

    k_transpose<<<dim3(LL / 32, EMBED / 32, BB), dim3(32, 8), 0, stream>>>(x, h0);

    const float* hin = h0;
    for (int mix = 0; mix < NMIX; mix++) {
        // in_proj: (NBL,192) x (768,192)^T -> xz (NBL,768)
        k_gemm_nt<<<dim3(768 / 64, NBL / 64), 256, 0, stream>>>(
            hin, EMBED, in_proj_w + (size_t)mix * 768 * EMBED, EMBED,
            xzb, 768, NBL, 768, EMBED);
        // conv + silu -> xa
        k_conv_silu<<<(NBL * DINNER) / 256, 256, 0, stream>>>(
            xzb, conv_w + mix * DINNER * DCONV, conv_b + mix * DINNER, xab);
        // x_proj -> x_dbl (NBL,20)
        k_xproj<<<NBL / 8, 256, 0, stream>>>(xab, x_proj_w + mix * 20 * DINNER, xdb);
        // dt_proj + softplus -> dt (NBL,384)
        k_dtproj<<<(NBL * DINNER) / 256, 256, 0, stream>>>(
            xdb, dt_proj_w + mix * DINNER * DTRANK, dt_proj_b + mix * DINNER, dtbf);
        // selective scan -> y into xz cols 0..383
        k_scan<<<(3072 * 4) / 256, 256, 0, stream>>>(
            dtbf, xab, xzb, xdb, A_log + mix * DINNER * DSTATE, Dp + mix * DINNER, xzb);
        // out_proj: y (lda=768) x (192,384)^T -> h1 (NBL,192)
        k_gemm_nt<<<dim3(EMBED / 64, NBL / 64), 256, 0, stream>>>(
            xzb, 768, out_proj_w + (size_t)mix * EMBED * DINNER, DINNER,
            h1, EMBED, NBL, EMBED, DINNER);
        hin = h1;
    }

    // low-rank + residual + LayerNorm -> out (B,C,H,W)
    k_lowrank_ln<<<NBL / 4, 256, 0, stream>>>(h1, h0, U_w, V_w, ln_g, ln_b, out);
}

// Round 2
// 1485.862 us; speedup vs baseline: 4.8300x; 4.8300x over previous
//
#include <hip/hip_runtime.h>
#include <hip/hip_bf16.h>
#include <cstdint>

// Problem constants
#define EMBED   192
#define DINNER  384
#define DSTATE  4
#define DCONV   4
#define DTRANK  12
#define NMIX    2
#define RANK    4
#define BB      8
#define LL      4096            // H*W = 64*64
#define NBL     (BB*LL)         // 32768 rows
#define NCHUNK  64
#define CLEN    64              // LL / NCHUNK

// ---------------------------------------------------------------------------
// Transpose (B, C, L) -> (B, L, C)
// ---------------------------------------------------------------------------
__global__ __launch_bounds__(256) void k_transpose(const float* __restrict__ x,
                                                   float* __restrict__ h0) {
    __shared__ float tile[32][33];
    int b  = blockIdx.z;
    int c0 = blockIdx.y * 32;
    int l0 = blockIdx.x * 32;
    int tx = threadIdx.x;       // 0..31
    int ty = threadIdx.y;       // 0..7
    #pragma unroll
    for (int i = 0; i < 4; i++) {
        int c = c0 + ty + i * 8;
        tile[ty + i * 8][tx] = x[((size_t)b * EMBED + c) * LL + l0 + tx];
    }
    __syncthreads();
    #pragma unroll
    for (int i = 0; i < 4; i++) {
        int l = l0 + ty + i * 8;
        h0[((size_t)b * LL + l) * EMBED + c0 + tx] = tile[tx][ty + i * 8];
    }
}

// ---------------------------------------------------------------------------
// Tiled SGEMM, "NT": C[m,n] = sum_k A[m*lda+k] * B[n*ldb+k]
// ---------------------------------------------------------------------------
__global__ __launch_bounds__(256) void k_gemm_nt(const float* __restrict__ A, int lda,
                                                 const float* __restrict__ Bw, int ldb,
                                                 float* __restrict__ C, int ldc,
                                                 int M, int N, int K) {
    __shared__ float As[16][65];
    __shared__ float Bs[16][65];
    int tid = threadIdx.x;
    int m0 = blockIdx.y * 64;
    int n0 = blockIdx.x * 64;
    int tm = (tid >> 4) * 4;
    int tn = (tid & 15) * 4;
    float acc[4][4] = {};
    for (int k0 = 0; k0 < K; k0 += 16) {
        #pragma unroll
        for (int i = 0; i < 4; i++) {
            int idx = tid + i * 256;
            int r = idx >> 4;
            int c = idx & 15;
            As[c][r] = A[(size_t)(m0 + r) * lda + k0 + c];
            Bs[c][r] = Bw[(size_t)(n0 + r) * ldb + k0 + c];
        }
        __syncthreads();
        #pragma unroll
        for (int kk = 0; kk < 16; kk++) {
            float a[4], b[4];
            #pragma unroll
            for (int i = 0; i < 4; i++) a[i] = As[kk][tm + i];
            #pragma unroll
            for (int j = 0; j < 4; j++) b[j] = Bs[kk][tn + j];
            #pragma unroll
            for (int i = 0; i < 4; i++)
                #pragma unroll
                for (int j = 0; j < 4; j++)
                    acc[i][j] += a[i] * b[j];
        }
        __syncthreads();
    }
    #pragma unroll
    for (int i = 0; i < 4; i++)
        #pragma unroll
        for (int j = 0; j < 4; j++)
            C[(size_t)(m0 + tm + i) * ldc + n0 + tn + j] = acc[i][j];
}

// ---------------------------------------------------------------------------
// Depthwise causal conv (width 4) + bias + SiLU.
// ---------------------------------------------------------------------------
__global__ __launch_bounds__(256) void k_conv_silu(const float* __restrict__ xz,
                                                   const float* __restrict__ cw,
                                                   const float* __restrict__ cb,
                                                   float* __restrict__ xa) {
    int gid = blockIdx.x * 256 + threadIdx.x;           // over NBL*384
    int d  = gid % DINNER;
    int bl = gid / DINNER;
    int l  = bl & (LL - 1);
    int b  = bl >> 12;
    float acc = cb[d];
    #pragma unroll
    for (int k = 0; k < DCONV; k++) {
        int ls = l - 3 + k;
        if (ls >= 0)
            acc += cw[d * DCONV + k] * xz[((size_t)(b * LL + ls)) * 768 + d];
    }
    float sg = 1.f / (1.f + __expf(-acc));
    xa[gid] = acc * sg;
}

// ---------------------------------------------------------------------------
// x_proj: x_dbl[m,e] = sum_k xa[m,k] * xpw[e,k], e in 0..19
// ---------------------------------------------------------------------------
__global__ __launch_bounds__(256) void k_xproj(const float* __restrict__ xa,
                                               const float* __restrict__ xpw,
                                               float* __restrict__ xdbl) {
    int tid = threadIdx.x;
    int e  = tid & 31;
    int mo = tid >> 5;
    int m  = blockIdx.x * 8 + mo;
    if (e >= 20) return;
    const float* a = xa + (size_t)m * DINNER;
    const float* w = xpw + e * DINNER;
    float s = 0.f;
    for (int k = 0; k < DINNER; k++) s += a[k] * w[k];
    xdbl[m * 20 + e] = s;
}

// ---------------------------------------------------------------------------
// Chunked selective scan, pass 1: per-chunk local scan from h=0.
// Block = 384 threads (lane = d), one block per (chunk, b).
// dt is recomputed inline (dt_proj row hoisted to registers + softplus).
// Emits per-chunk (Aprod, h_final) per state, laid out [chain][chunk],
// chain = (b*384+d)*4+s.
// ---------------------------------------------------------------------------
__global__ __launch_bounds__(384) void k_scan_local(const float* __restrict__ xa,
                                                    const float* __restrict__ xdbl,
                                                    const float* __restrict__ dtw,
                                                    const float* __restrict__ dtb,
                                                    const float* __restrict__ A_log,
                                                    float* __restrict__ carryA,
                                                    float* __restrict__ carryH) {
    int d     = threadIdx.x;
    int chunk = blockIdx.x;
    int b     = blockIdx.y;
    float w[DTRANK];
    #pragma unroll
    for (int r = 0; r < DTRANK; r++) w[r] = dtw[d * DTRANK + r];
    float As[DSTATE];
    #pragma unroll
    for (int s = 0; s < DSTATE; s++) As[s] = -__expf(A_log[d * DSTATE + s]);
    float bias = dtb[d];
    float h[DSTATE]  = {0.f, 0.f, 0.f, 0.f};
    float ap[DSTATE] = {1.f, 1.f, 1.f, 1.f};
    size_t mbase = (size_t)b * LL + (size_t)chunk * CLEN;
    for (int i = 0; i < CLEN; i++) {
        size_t m = mbase + i;
        const float* row = xdbl + m * 20;   // uniform across block
        float acc = bias;
        #pragma unroll
        for (int r = 0; r < DTRANK; r++) acc += row[r] * w[r];
        float dtv = fmaxf(acc, 0.f) + log1pf(__expf(-fabsf(acc)));
        float xav = xa[m * DINNER + d];
        float du  = dtv * xav;
        #pragma unroll
        for (int s = 0; s < DSTATE; s++) {
            float da = __expf(dtv * As[s]);
            h[s]  = da * h[s] + du * row[DTRANK + s];
            ap[s] *= da;
        }
    }
    size_t cbase = ((size_t)(b * DINNER + d) * DSTATE) * NCHUNK + chunk;
    #pragma unroll
    for (int s = 0; s < DSTATE; s++) {
        carryA[cbase + (size_t)s * NCHUNK] = ap[s];
        carryH[cbase + (size_t)s * NCHUNK] = h[s];
    }
}

// ---------------------------------------------------------------------------
// Chunked scan, pass 2: wave-level scan over chunks (lane = chunk).
// Compose (A1,B1)∘(A2,B2) = (A1*A2, A2*B1+B2). Writes incoming state per
// chunk (exclusive scan result) back into carryH.
// ---------------------------------------------------------------------------
__global__ __launch_bounds__(256) void k_scan_combine(const float* __restrict__ carryA,
                                                      float* __restrict__ carryH) {
    int lane  = threadIdx.x & 63;
    int chain = blockIdx.x * 4 + (threadIdx.x >> 6);
    size_t idx = (size_t)chain * NCHUNK + lane;
    float A  = carryA[idx];
    float Bv = carryH[idx];
    #pragma unroll
    for (int off = 1; off < 64; off <<= 1) {
        float Aj = __shfl_up(A, off, 64);
        float Bj = __shfl_up(Bv, off, 64);
        if (lane >= off) {
            Bv = A * Bj + Bv;   // uses old A (right operand's Aprefix)
            A  = A * Aj;
        }
    }
    float hin = __shfl_up(Bv, 1, 64);
    if (lane == 0) hin = 0.f;
    carryH[idx] = hin;
}

// ---------------------------------------------------------------------------
// Chunked scan, pass 3: rerun local scan seeded with incoming state; fuse
// y = h·C + xa*D, y *= silu(z); write into xz cols 0..383 (dead xin half).
// ---------------------------------------------------------------------------
__global__ __launch_bounds__(384) void k_scan_final(const float* __restrict__ xa,
                                                    const float* __restrict__ xz,
                                                    const float* __restrict__ xdbl,
                                                    const float* __restrict__ dtw,
                                                    const float* __restrict__ dtb,
                                                    const float* __restrict__ A_log,
                                                    const float* __restrict__ Dp,
                                                    const float* __restrict__ carryH,
                                                    float* __restrict__ y) {
    int d     = threadIdx.x;
    int chunk = blockIdx.x;
    int b     = blockIdx.y;
    float w[DTRANK];
    #pragma unroll
    for (int r = 0; r < DTRANK; r++) w[r] = dtw[d * DTRANK + r];
    float As[DSTATE];
    #pragma unroll
    for (int s = 0; s < DSTATE; s++) As[s] = -__expf(A_log[d * DSTATE + s]);
    float bias = dtb[d];
    float Dd   = Dp[d];
    size_t cbase = ((size_t)(b * DINNER + d) * DSTATE) * NCHUNK + chunk;
    float h[DSTATE];
    #pragma unroll
    for (int s = 0; s < DSTATE; s++) h[s] = carryH[cbase + (size_t)s * NCHUNK];
    size_t mbase = (size_t)b * LL + (size_t)chunk * CLEN;
    for (int i = 0; i < CLEN; i++) {
        size_t m = mbase + i;
        const float* row = xdbl + m * 20;
        float acc = bias;
        #pragma unroll
        for (int r = 0; r < DTRANK; r++) acc += row[r] * w[r];
        float dtv = fmaxf(acc, 0.f) + log1pf(__expf(-fabsf(acc)));
        float xav = xa[m * DINNER + d];
        float du  = dtv * xav;
        float yv  = 0.f;
        #pragma unroll
        for (int s = 0; s < DSTATE; s++) {
            float da = __expf(dtv * As[s]);
            h[s] = da * h[s] + du * row[DTRANK + s];
            yv  += h[s] * row[DTRANK + DSTATE + s];
        }
        yv += xav * Dd;
        float zv = xz[m * 768 + DINNER + d];
        yv *= zv / (1.f + __expf(-zv));
        y[m * 768 + d] = yv;
    }
}

// ---------------------------------------------------------------------------
// Low-rank (U then V) + residual + LayerNorm over C, write (B,C,L).
// ---------------------------------------------------------------------------
__global__ __launch_bounds__(256) void k_lowrank_ln(const float* __restrict__ h2,
                                                    const float* __restrict__ h0,
                                                    const float* __restrict__ U,
                                                    const float* __restrict__ V,
                                                    const float* __restrict__ g,
                                                    const float* __restrict__ be,
                                                    float* __restrict__ out) {
    int wid  = threadIdx.x >> 6;
    int lane = threadIdx.x & 63;
    int m = blockIdx.x * 4 + wid;       // 0..NBL-1
    int b = m >> 12;
    int l = m & (LL - 1);
    const float* hr  = h2 + (size_t)m * EMBED;
    const float* h0r = h0 + (size_t)m * EMBED;
    float hv[3];
    #pragma unroll
    for (int i = 0; i < 3; i++) hv[i] = hr[lane + 64 * i];
    float r[RANK];
    #pragma unroll
    for (int j = 0; j < RANK; j++) {
        float p = 0.f;
        #pragma unroll
        for (int i = 0; i < 3; i++) p += hv[i] * U[j * EMBED + lane + 64 * i];
        #pragma unroll
        for (int off = 1; off < 64; off <<= 1) p += __shfl_xor(p, off);
        r[j] = p;
    }
    float u[3], s1 = 0.f, s2 = 0.f;
    #pragma unroll
    for (int i = 0; i < 3; i++) {
        int c = lane + 64 * i;
        float v = r[0] * V[c * 4 + 0] + r[1] * V[c * 4 + 1]
                + r[2] * V[c * 4 + 2] + r[3] * V[c * 4 + 3];
        u[i] = v + h0r[c];
        s1 += u[i];
        s2 += u[i] * u[i];
    }
    #pragma unroll
    for (int off = 1; off < 64; off <<= 1) {
        s1 += __shfl_xor(s1, off);
        s2 += __shfl_xor(s2, off);
    }
    float mean = s1 * (1.f / EMBED);
    float var  = s2 * (1.f / EMBED) - mean * mean;
    float inv  = rsqrtf(var + 1e-5f);
    #pragma unroll
    for (int i = 0; i < 3; i++) {
        int c = lane + 64 * i;
        out[((size_t)(b * EMBED + c)) * LL + l] = (u[i] - mean) * inv * g[c] + be[c];
    }
}

// ---------------------------------------------------------------------------
extern "C" void kernel_launch(void* const* d_in, const int* in_sizes, int n_in,
                              void* d_out, int out_size, void* d_ws, size_t ws_size,
                              hipStream_t stream) {
    const float* x          = (const float*)d_in[0];
    const float* in_proj_w  = (const float*)d_in[1];
    const float* conv_w     = (const float*)d_in[2];
    const float* conv_b     = (const float*)d_in[3];
    const float* x_proj_w   = (const float*)d_in[4];
    const float* dt_proj_w  = (const float*)d_in[5];
    const float* dt_proj_b  = (const float*)d_in[6];
    const float* A_log      = (const float*)d_in[7];
    const float* Dp         = (const float*)d_in[8];
    const float* out_proj_w = (const float*)d_in[9];
    const float* U_w        = (const float*)d_in[10];
    const float* V_w        = (const float*)d_in[11];
    const float* ln_g       = (const float*)d_in[12];
    const float* ln_b       = (const float*)d_in[13];
    float* out = (float*)d_out;

    // Workspace layout (floats). Total ~201 MiB.
    float* ws   = (float*)d_ws;
    float* h0   = ws;                          // NBL*192
    float* h1   = h0  + (size_t)NBL * EMBED;   // NBL*192
    float* xzb  = h1  + (size_t)NBL * EMBED;   // NBL*768
    float* xab  = xzb + (size_t)NBL * 768;     // NBL*384
    float* xdb  = xab + (size_t)NBL * DINNER;  // NBL*20
    float* cA   = xdb + (size_t)NBL * 20;      // 8*64*384*4 = 786432
    float* cH   = cA  + (size_t)BB * NCHUNK * DINNER * DSTATE;

    k_transpose<<<dim3(LL / 32, EMBED / 32, BB), dim3(32, 8), 0, stream>>>(x, h0);

    const float* hin = h0;
    for (int mix = 0; mix < NMIX; mix++) {
        const float* dtw = dt_proj_w + (size_t)mix * DINNER * DTRANK;
        const float* dtb = dt_proj_b + (size_t)mix * DINNER;
        const float* Alg = A_log + (size_t)mix * DINNER * DSTATE;

        // in_proj: (NBL,192) x (768,192)^T -> xz (NBL,768)
        k_gemm_nt<<<dim3(768 / 64, NBL / 64), 256, 0, stream>>>(
            hin, EMBED, in_proj_w + (size_t)mix * 768 * EMBED, EMBED,
            xzb, 768, NBL, 768, EMBED);
        // conv + silu -> xa
        k_conv_silu<<<(NBL * DINNER) / 256, 256, 0, stream>>>(
            xzb, conv_w + mix * DINNER * DCONV, conv_b + mix * DINNER, xab);
        // x_proj -> x_dbl (NBL,20)
        k_xproj<<<NBL / 8, 256, 0, stream>>>(xab, x_proj_w + mix * 20 * DINNER, xdb);
        // chunked scan
        k_scan_local<<<dim3(NCHUNK, BB), 384, 0, stream>>>(
            xab, xdb, dtw, dtb, Alg, cA, cH);
        k_scan_combine<<<(BB * DINNER * DSTATE) / 4, 256, 0, stream>>>(cA, cH);
        k_scan_final<<<dim3(NCHUNK, BB), 384, 0, stream>>>(
            xab, xzb, xdb, dtw, dtb, Alg, Dp + mix * DINNER, cH, xzb);
        // out_proj: y (lda=768) x (192,384)^T -> h1 (NBL,192)
        k_gemm_nt<<<dim3(EMBED / 64, NBL / 64), 256, 0, stream>>>(
            xzb, 768, out_proj_w + (size_t)mix * EMBED * DINNER, DINNER,
            h1, EMBED, NBL, EMBED, DINNER);
        hin = h1;
    }

    // low-rank + residual + LayerNorm -> out (B,C,H,W)
    k_lowrank_ln<<<NBL / 4, 256, 0, stream>>>(h1, h0, U_w, V_w, ln_g, ln_b, out);
}

// Round 3
// 805.574 us; speedup vs baseline: 8.9089x; 1.8445x over previous
//
#include <hip/hip_runtime.h>
#include <hip/hip_bf16.h>
#include <cstdint>

// Problem constants
#define EMBED   192
#define DINNER  384
#define DSTATE  4
#define DCONV   4
#define DTRANK  12
#define NMIX    2
#define RANK    4
#define BB      8
#define LL      4096            // H*W = 64*64
#define NBL     (BB*LL)         // 32768 rows
#define NCHUNK  64
#define CLEN    64              // LL / NCHUNK

typedef __attribute__((ext_vector_type(8))) short short8;
typedef __attribute__((ext_vector_type(4))) float float4v;

static __device__ __forceinline__ ushort f2b(float f) {
    __hip_bfloat16 h = __float2bfloat16(f);
    return *(ushort*)&h;
}
static __device__ __forceinline__ float b2f(ushort u) {
    __hip_bfloat16 h;
    *(ushort*)&h = u;
    return __bfloat162float(h);
}

// ---------------------------------------------------------------------------
// fp32 -> bf16 cast (weights)
// ---------------------------------------------------------------------------
__global__ __launch_bounds__(256) void k_cast(const float* __restrict__ src,
                                              ushort* __restrict__ dst, int n) {
    int i = blockIdx.x * 256 + threadIdx.x;
    if (i < n) dst[i] = f2b(src[i]);
}

// ---------------------------------------------------------------------------
// Transpose (B, C, L) -> (B, L, C); fp32 out (residual) + bf16 out (GEMM A)
// ---------------------------------------------------------------------------
__global__ __launch_bounds__(256) void k_transpose(const float* __restrict__ x,
                                                   float* __restrict__ h0,
                                                   ushort* __restrict__ h0b) {
    __shared__ float tile[32][33];
    int b  = blockIdx.z;
    int c0 = blockIdx.y * 32;
    int l0 = blockIdx.x * 32;
    int tx = threadIdx.x;       // 0..31
    int ty = threadIdx.y;       // 0..7
    #pragma unroll
    for (int i = 0; i < 4; i++) {
        int c = c0 + ty + i * 8;
        tile[ty + i * 8][tx] = x[((size_t)b * EMBED + c) * LL + l0 + tx];
    }
    __syncthreads();
    #pragma unroll
    for (int i = 0; i < 4; i++) {
        int l = l0 + ty + i * 8;
        float v = tile[tx][ty + i * 8];
        size_t o = ((size_t)b * LL + l) * EMBED + c0 + tx;
        h0[o]  = v;
        h0b[o] = f2b(v);
    }
}

// ---------------------------------------------------------------------------
// bf16 MFMA GEMM, NT: C[m,n] = sum_k A[m,k]*B[n,k]. M=32768 (grid.y*128).
// TN in {128 (WRN=2, wave=64x64), 64 (WRN=1, wave=32x64)}. BK=32.
// Writes fp32 C (if non-null) and/or bf16 Cb (if non-null).
// ---------------------------------------------------------------------------
template<int TN, int WRN>
__global__ __launch_bounds__(256) void k_gemm_bf16(const ushort* __restrict__ A, int lda,
                                                   const ushort* __restrict__ Bw, int ldb,
                                                   float* __restrict__ C, int ldc,
                                                   ushort* __restrict__ Cb, int ldcb,
                                                   int K) {
    constexpr int WRM = 4 / WRN;
    constexpr int WM  = 128 / WRM;       // wave tile M: 64 or 32
    constexpr int MT  = WM / 16;         // MFMA tiles in M per wave
    __shared__ ushort As[128][40];       // +8 pad: 80B row stride
    __shared__ ushort Bs[TN][40];
    int tid  = threadIdx.x;
    int lane = tid & 63;
    int wave = tid >> 6;
    int wmo = (wave / WRN) * WM;
    int wno = (wave % WRN) * 64;
    int m0 = blockIdx.y * 128;
    int n0 = blockIdx.x * TN;

    float4v acc[MT][4];
    #pragma unroll
    for (int i = 0; i < MT; i++)
        #pragma unroll
        for (int j = 0; j < 4; j++)
            acc[i][j] = (float4v){0.f, 0.f, 0.f, 0.f};

    for (int k0 = 0; k0 < K; k0 += 32) {
        #pragma unroll
        for (int i = 0; i < 2; i++) {
            int idx = tid + i * 256;
            int r = idx >> 2, sg = idx & 3;
            *(short8*)&As[r][sg * 8] =
                *(const short8*)(A + (size_t)(m0 + r) * lda + k0 + sg * 8);
        }
        #pragma unroll
        for (int i = 0; i < TN / 64; i++) {
            int idx = tid + i * 256;
            int r = idx >> 2, sg = idx & 3;
            *(short8*)&Bs[r][sg * 8] =
                *(const short8*)(Bw + (size_t)(n0 + r) * ldb + k0 + sg * 8);
        }
        __syncthreads();
        short8 av[MT], bv[4];
        #pragma unroll
        for (int i = 0; i < MT; i++)
            av[i] = *(const short8*)&As[wmo + i * 16 + (lane & 15)][(lane >> 4) * 8];
        #pragma unroll
        for (int j = 0; j < 4; j++)
            bv[j] = *(const short8*)&Bs[wno + j * 16 + (lane & 15)][(lane >> 4) * 8];
        #pragma unroll
        for (int i = 0; i < MT; i++)
            #pragma unroll
            for (int j = 0; j < 4; j++)
                acc[i][j] = __builtin_amdgcn_mfma_f32_16x16x32_bf16(
                    av[i], bv[j], acc[i][j], 0, 0, 0);
        __syncthreads();
    }

    #pragma unroll
    for (int i = 0; i < MT; i++) {
        int rbase = m0 + wmo + i * 16 + (lane >> 4) * 4;
        #pragma unroll
        for (int j = 0; j < 4; j++) {
            int col = n0 + wno + j * 16 + (lane & 15);
            #pragma unroll
            for (int r = 0; r < 4; r++) {
                float v = acc[i][j][r];
                if (C)  C[(size_t)(rbase + r) * ldc + col] = v;
                if (Cb) Cb[(size_t)(rbase + r) * ldcb + col] = f2b(v);
            }
        }
    }
}

// ---------------------------------------------------------------------------
// Depthwise causal conv (width 4) + bias + SiLU. bf16 in (xin half of xz),
// bf16 out.
// ---------------------------------------------------------------------------
__global__ __launch_bounds__(256) void k_conv_silu(const ushort* __restrict__ xz,
                                                   const float* __restrict__ cw,
                                                   const float* __restrict__ cb,
                                                   ushort* __restrict__ xa) {
    int gid = blockIdx.x * 256 + threadIdx.x;           // over NBL*384
    int d  = gid % DINNER;
    int bl = gid / DINNER;
    int l  = bl & (LL - 1);
    int b  = bl >> 12;
    float acc = cb[d];
    #pragma unroll
    for (int k = 0; k < DCONV; k++) {
        int ls = l - 3 + k;
        if (ls >= 0)
            acc += cw[d * DCONV + k] * b2f(xz[((size_t)(b * LL + ls)) * 768 + d]);
    }
    float sg = 1.f / (1.f + __expf(-acc));
    xa[gid] = f2b(acc * sg);
}

// ---------------------------------------------------------------------------
// x_proj: wave per row, coalesced xa loads, shuffle reduce. 20 outputs/row.
// ---------------------------------------------------------------------------
__global__ __launch_bounds__(256) void k_xproj(const ushort* __restrict__ xa,
                                               const float* __restrict__ xpw,
                                               float* __restrict__ xdbl) {
    int lane = threadIdx.x & 63;
    int m = blockIdx.x * 4 + (threadIdx.x >> 6);
    const ushort* a = xa + (size_t)m * DINNER;
    float av[6];
    #pragma unroll
    for (int i = 0; i < 6; i++) av[i] = b2f(a[lane + 64 * i]);
    for (int e = 0; e < 20; e++) {
        const float* w = xpw + e * DINNER;
        float s = 0.f;
        #pragma unroll
        for (int i = 0; i < 6; i++) s += av[i] * w[lane + 64 * i];
        #pragma unroll
        for (int off = 1; off < 64; off <<= 1) s += __shfl_xor(s, off);
        if (lane == 0) xdbl[m * 20 + e] = s;
    }
}

// ---------------------------------------------------------------------------
// Chunked selective scan, pass 1: per-chunk local scan from h=0.
// ---------------------------------------------------------------------------
__global__ __launch_bounds__(384) void k_scan_local(const ushort* __restrict__ xa,
                                                    const float* __restrict__ xdbl,
                                                    const float* __restrict__ dtw,
                                                    const float* __restrict__ dtb,
                                                    const float* __restrict__ A_log,
                                                    float* __restrict__ carryA,
                                                    float* __restrict__ carryH) {
    int d     = threadIdx.x;
    int chunk = blockIdx.x;
    int b     = blockIdx.y;
    float w[DTRANK];
    #pragma unroll
    for (int r = 0; r < DTRANK; r++) w[r] = dtw[d * DTRANK + r];
    float As[DSTATE];
    #pragma unroll
    for (int s = 0; s < DSTATE; s++) As[s] = -__expf(A_log[d * DSTATE + s]);
    float bias = dtb[d];
    float h[DSTATE]  = {0.f, 0.f, 0.f, 0.f};
    float ap[DSTATE] = {1.f, 1.f, 1.f, 1.f};
    size_t mbase = (size_t)b * LL + (size_t)chunk * CLEN;
    for (int i = 0; i < CLEN; i++) {
        size_t m = mbase + i;
        const float* row = xdbl + m * 20;   // uniform across block
        float acc = bias;
        #pragma unroll
        for (int r = 0; r < DTRANK; r++) acc += row[r] * w[r];
        float dtv = fmaxf(acc, 0.f) + log1pf(__expf(-fabsf(acc)));
        float xav = b2f(xa[m * DINNER + d]);
        float du  = dtv * xav;
        #pragma unroll
        for (int s = 0; s < DSTATE; s++) {
            float da = __expf(dtv * As[s]);
            h[s]  = da * h[s] + du * row[DTRANK + s];
            ap[s] *= da;
        }
    }
    size_t cbase = ((size_t)(b * DINNER + d) * DSTATE) * NCHUNK + chunk;
    #pragma unroll
    for (int s = 0; s < DSTATE; s++) {
        carryA[cbase + (size_t)s * NCHUNK] = ap[s];
        carryH[cbase + (size_t)s * NCHUNK] = h[s];
    }
}

// ---------------------------------------------------------------------------
// Chunked scan, pass 2: wave-level scan over chunks (lane = chunk).
// ---------------------------------------------------------------------------
__global__ __launch_bounds__(256) void k_scan_combine(const float* __restrict__ carryA,
                                                      float* __restrict__ carryH) {
    int lane  = threadIdx.x & 63;
    int chain = blockIdx.x * 4 + (threadIdx.x >> 6);
    size_t idx = (size_t)chain * NCHUNK + lane;
    float A  = carryA[idx];
    float Bv = carryH[idx];
    #pragma unroll
    for (int off = 1; off < 64; off <<= 1) {
        float Aj = __shfl_up(A, off, 64);
        float Bj = __shfl_up(Bv, off, 64);
        if (lane >= off) {
            Bv = A * Bj + Bv;
            A  = A * Aj;
        }
    }
    float hin = __shfl_up(Bv, 1, 64);
    if (lane == 0) hin = 0.f;
    carryH[idx] = hin;
}

// ---------------------------------------------------------------------------
// Chunked scan, pass 3: seeded rerun; fuse y = h·C + xa*D, y *= silu(z);
// write bf16 y (out_proj A operand).
// ---------------------------------------------------------------------------
__global__ __launch_bounds__(384) void k_scan_final(const ushort* __restrict__ xa,
                                                    const ushort* __restrict__ xz,
                                                    const float* __restrict__ xdbl,
                                                    const float* __restrict__ dtw,
                                                    const float* __restrict__ dtb,
                                                    const float* __restrict__ A_log,
                                                    const float* __restrict__ Dp,
                                                    const float* __restrict__ carryH,
                                                    ushort* __restrict__ y) {
    int d     = threadIdx.x;
    int chunk = blockIdx.x;
    int b     = blockIdx.y;
    float w[DTRANK];
    #pragma unroll
    for (int r = 0; r < DTRANK; r++) w[r] = dtw[d * DTRANK + r];
    float As[DSTATE];
    #pragma unroll
    for (int s = 0; s < DSTATE; s++) As[s] = -__expf(A_log[d * DSTATE + s]);
    float bias = dtb[d];
    float Dd   = Dp[d];
    size_t cbase = ((size_t)(b * DINNER + d) * DSTATE) * NCHUNK + chunk;
    float h[DSTATE];
    #pragma unroll
    for (int s = 0; s < DSTATE; s++) h[s] = carryH[cbase + (size_t)s * NCHUNK];
    size_t mbase = (size_t)b * LL + (size_t)chunk * CLEN;
    for (int i = 0; i < CLEN; i++) {
        size_t m = mbase + i;
        const float* row = xdbl + m * 20;
        float acc = bias;
        #pragma unroll
        for (int r = 0; r < DTRANK; r++) acc += row[r] * w[r];
        float dtv = fmaxf(acc, 0.f) + log1pf(__expf(-fabsf(acc)));
        float xav = b2f(xa[m * DINNER + d]);
        float du  = dtv * xav;
        float yv  = 0.f;
        #pragma unroll
        for (int s = 0; s < DSTATE; s++) {
            float da = __expf(dtv * As[s]);
            h[s] = da * h[s] + du * row[DTRANK + s];
            yv  += h[s] * row[DTRANK + DSTATE + s];
        }
        yv += xav * Dd;
        float zv = b2f(xz[m * 768 + DINNER + d]);
        yv *= zv / (1.f + __expf(-zv));
        y[m * DINNER + d] = f2b(yv);
    }
}

// ---------------------------------------------------------------------------
// Low-rank (U then V) + residual + LayerNorm over C, write (B,C,L).
// ---------------------------------------------------------------------------
__global__ __launch_bounds__(256) void k_lowrank_ln(const float* __restrict__ h2,
                                                    const float* __restrict__ h0,
                                                    const float* __restrict__ U,
                                                    const float* __restrict__ V,
                                                    const float* __restrict__ g,
                                                    const float* __restrict__ be,
                                                    float* __restrict__ out) {
    int wid  = threadIdx.x >> 6;
    int lane = threadIdx.x & 63;
    int m = blockIdx.x * 4 + wid;       // 0..NBL-1
    int b = m >> 12;
    int l = m & (LL - 1);
    const float* hr  = h2 + (size_t)m * EMBED;
    const float* h0r = h0 + (size_t)m * EMBED;
    float hv[3];
    #pragma unroll
    for (int i = 0; i < 3; i++) hv[i] = hr[lane + 64 * i];
    float r[RANK];
    #pragma unroll
    for (int j = 0; j < RANK; j++) {
        float p = 0.f;
        #pragma unroll
        for (int i = 0; i < 3; i++) p += hv[i] * U[j * EMBED + lane + 64 * i];
        #pragma unroll
        for (int off = 1; off < 64; off <<= 1) p += __shfl_xor(p, off);
        r[j] = p;
    }
    float u[3], s1 = 0.f, s2 = 0.f;
    #pragma unroll
    for (int i = 0; i < 3; i++) {
        int c = lane + 64 * i;
        float v = r[0] * V[c * 4 + 0] + r[1] * V[c * 4 + 1]
                + r[2] * V[c * 4 + 2] + r[3] * V[c * 4 + 3];
        u[i] = v + h0r[c];
        s1 += u[i];
        s2 += u[i] * u[i];
    }
    #pragma unroll
    for (int off = 1; off < 64; off <<= 1) {
        s1 += __shfl_xor(s1, off);
        s2 += __shfl_xor(s2, off);
    }
    float mean = s1 * (1.f / EMBED);
    float var  = s2 * (1.f / EMBED) - mean * mean;
    float inv  = rsqrtf(var + 1e-5f);
    #pragma unroll
    for (int i = 0; i < 3; i++) {
        int c = lane + 64 * i;
        out[((size_t)(b * EMBED + c)) * LL + l] = (u[i] - mean) * inv * g[c] + be[c];
    }
}

// ---------------------------------------------------------------------------
extern "C" void kernel_launch(void* const* d_in, const int* in_sizes, int n_in,
                              void* d_out, int out_size, void* d_ws, size_t ws_size,
                              hipStream_t stream) {
    const float* x          = (const float*)d_in[0];
    const float* in_proj_w  = (const float*)d_in[1];
    const float* conv_w     = (const float*)d_in[2];
    const float* conv_b     = (const float*)d_in[3];
    const float* x_proj_w   = (const float*)d_in[4];
    const float* dt_proj_w  = (const float*)d_in[5];
    const float* dt_proj_b  = (const float*)d_in[6];
    const float* A_log      = (const float*)d_in[7];
    const float* Dp         = (const float*)d_in[8];
    const float* out_proj_w = (const float*)d_in[9];
    const float* U_w        = (const float*)d_in[10];
    const float* V_w        = (const float*)d_in[11];
    const float* ln_g       = (const float*)d_in[12];
    const float* ln_b       = (const float*)d_in[13];
    float* out = (float*)d_out;

    // Workspace layout (~186 MiB).
    float* ws  = (float*)d_ws;
    float* h0  = ws;                              // NBL*192 f32
    float* h1  = h0  + (size_t)NBL * EMBED;       // NBL*192 f32
    float* xdb = h1  + (size_t)NBL * EMBED;       // NBL*20  f32
    float* cA  = xdb + (size_t)NBL * 20;          // 786432  f32
    float* cH  = cA  + (size_t)BB * NCHUNK * DINNER * DSTATE;
    ushort* xz16 = (ushort*)(cH + (size_t)BB * NCHUNK * DINNER * DSTATE);
    ushort* xa16 = xz16 + (size_t)NBL * 768;      // NBL*384 bf16
    ushort* yb   = xa16 + (size_t)NBL * DINNER;   // NBL*384 bf16
    ushort* h0b  = yb   + (size_t)NBL * DINNER;   // NBL*192 bf16
    ushort* h1b  = h0b  + (size_t)NBL * EMBED;    // NBL*192 bf16
    ushort* wi   = h1b  + (size_t)NBL * EMBED;    // 2*768*192 bf16
    ushort* wo   = wi   + (size_t)NMIX * 768 * EMBED; // 2*192*384 bf16

    const int n_wi = NMIX * 768 * EMBED;   // 294912
    const int n_wo = NMIX * EMBED * DINNER; // 147456
    k_cast<<<(n_wi + 255) / 256, 256, 0, stream>>>(in_proj_w, wi, n_wi);
    k_cast<<<(n_wo + 255) / 256, 256, 0, stream>>>(out_proj_w, wo, n_wo);

    k_transpose<<<dim3(LL / 32, EMBED / 32, BB), dim3(32, 8), 0, stream>>>(x, h0, h0b);

    const ushort* hinb = h0b;
    for (int mix = 0; mix < NMIX; mix++) {
        const float* dtw = dt_proj_w + (size_t)mix * DINNER * DTRANK;
        const float* dtb = dt_proj_b + (size_t)mix * DINNER;
        const float* Alg = A_log + (size_t)mix * DINNER * DSTATE;

        // in_proj: (32768,192)bf16 x (768,192)^T bf16 -> xz bf16 (NBL,768)
        k_gemm_bf16<128, 2><<<dim3(768 / 128, NBL / 128), 256, 0, stream>>>(
            hinb, EMBED, wi + (size_t)mix * 768 * EMBED, EMBED,
            (float*)nullptr, 0, xz16, 768, EMBED);
        // conv + silu -> xa bf16
        k_conv_silu<<<(NBL * DINNER) / 256, 256, 0, stream>>>(
            xz16, conv_w + mix * DINNER * DCONV, conv_b + mix * DINNER, xa16);
        // x_proj -> x_dbl (NBL,20) f32
        k_xproj<<<NBL / 4, 256, 0, stream>>>(xa16, x_proj_w + mix * 20 * DINNER, xdb);
        // chunked scan
        k_scan_local<<<dim3(NCHUNK, BB), 384, 0, stream>>>(
            xa16, xdb, dtw, dtb, Alg, cA, cH);
        k_scan_combine<<<(BB * DINNER * DSTATE) / 4, 256, 0, stream>>>(cA, cH);
        k_scan_final<<<dim3(NCHUNK, BB), 384, 0, stream>>>(
            xa16, xz16, xdb, dtw, dtb, Alg, Dp + mix * DINNER, cH, yb);
        // out_proj: y (32768,384)bf16 x (192,384)^T bf16 -> h1 f32 + h1b bf16
        k_gemm_bf16<64, 1><<<dim3(EMBED / 64, NBL / 128), 256, 0, stream>>>(
            yb, DINNER, wo + (size_t)mix * EMBED * DINNER, DINNER,
            h1, EMBED, h1b, EMBED, DINNER);
        hinb = h1b;
    }

    // low-rank + residual + LayerNorm -> out (B,C,H,W)
    k_lowrank_ln<<<NBL / 4, 256, 0, stream>>>(h1, h0, U_w, V_w, ln_g, ln_b, out);
}

// Round 4
// 605.135 us; speedup vs baseline: 11.8597x; 1.3312x over previous
//
#include <hip/hip_runtime.h>
#include <hip/hip_bf16.h>
#include <cstdint>

// Problem constants
#define EMBED   192
#define DINNER  384
#define DSTATE  4
#define DCONV   4
#define DTRANK  12
#define NMIX    2
#define RANK    4
#define BB      8
#define LL      4096            // H*W = 64*64
#define NBL     (BB*LL)         // 32768 rows
#define NCHUNK  128
#define CLEN    32              // LL / NCHUNK

typedef __attribute__((ext_vector_type(8))) short short8;
typedef __attribute__((ext_vector_type(4))) float float4v;

static __device__ __forceinline__ ushort f2b(float f) {
    __hip_bfloat16 h = __float2bfloat16(f);
    return *(ushort*)&h;
}
static __device__ __forceinline__ float b2f(ushort u) {
    __hip_bfloat16 h;
    *(ushort*)&h = u;
    return __bfloat162float(h);
}

// ---------------------------------------------------------------------------
// fp32 -> bf16 cast (weights)
// ---------------------------------------------------------------------------
__global__ __launch_bounds__(256) void k_cast(const float* __restrict__ src,
                                              ushort* __restrict__ dst, int n) {
    int i = blockIdx.x * 256 + threadIdx.x;
    if (i < n) dst[i] = f2b(src[i]);
}

// x_proj weights: (NMIX,20,384) -> bf16 padded (NMIX,32,384), rows 20..31 = 0
__global__ __launch_bounds__(256) void k_pad_xpw(const float* __restrict__ src,
                                                 ushort* __restrict__ dst) {
    int i = blockIdx.x * 256 + threadIdx.x;
    if (i >= NMIX * 32 * 384) return;
    int mix = i / (32 * 384);
    int rem = i % (32 * 384);
    int e = rem / 384, k = rem % 384;
    dst[i] = (e < 20) ? f2b(src[(size_t)mix * 20 * 384 + e * 384 + k]) : (ushort)0;
}

// dt_proj weights: (NMIX,384,12) -> bf16 padded (NMIX,384,32), cols 12..31 = 0
__global__ __launch_bounds__(256) void k_pad_dtw(const float* __restrict__ src,
                                                 ushort* __restrict__ dst) {
    int i = blockIdx.x * 256 + threadIdx.x;
    if (i >= NMIX * 384 * 32) return;
    int mix = i / (384 * 32);
    int rem = i % (384 * 32);
    int n = rem / 32, r = rem % 32;
    dst[i] = (r < DTRANK) ? f2b(src[(size_t)mix * 384 * DTRANK + n * DTRANK + r]) : (ushort)0;
}

// ---------------------------------------------------------------------------
// Transpose (B, C, L) -> (B, L, C) bf16 only (residual re-read from x later)
// ---------------------------------------------------------------------------
__global__ __launch_bounds__(256) void k_transpose(const float* __restrict__ x,
                                                   ushort* __restrict__ h0b) {
    __shared__ float tile[32][33];
    int b  = blockIdx.z;
    int c0 = blockIdx.y * 32;
    int l0 = blockIdx.x * 32;
    int tx = threadIdx.x;       // 0..31
    int ty = threadIdx.y;       // 0..7
    #pragma unroll
    for (int i = 0; i < 4; i++) {
        int c = c0 + ty + i * 8;
        tile[ty + i * 8][tx] = x[((size_t)b * EMBED + c) * LL + l0 + tx];
    }
    __syncthreads();
    #pragma unroll
    for (int i = 0; i < 4; i++) {
        int l = l0 + ty + i * 8;
        h0b[((size_t)b * LL + l) * EMBED + c0 + tx] = f2b(tile[tx][ty + i * 8]);
    }
}

// ---------------------------------------------------------------------------
// bf16 MFMA GEMM, NT: C[m,n] = sum_k A[m,k]*B[n,k]. M=32768 (grid.y*128).
// TN in {128 (WRN=2), 64 (WRN=1)}. BK=32. Writes fp32 C and/or bf16 Cb.
// ---------------------------------------------------------------------------
template<int TN, int WRN>
__global__ __launch_bounds__(256) void k_gemm_bf16(const ushort* __restrict__ A, int lda,
                                                   const ushort* __restrict__ Bw, int ldb,
                                                   float* __restrict__ C, int ldc,
                                                   ushort* __restrict__ Cb, int ldcb,
                                                   int K) {
    constexpr int WRM = 4 / WRN;
    constexpr int WM  = 128 / WRM;
    constexpr int MT  = WM / 16;
    __shared__ ushort As[128][40];
    __shared__ ushort Bs[TN][40];
    int tid  = threadIdx.x;
    int lane = tid & 63;
    int wave = tid >> 6;
    int wmo = (wave / WRN) * WM;
    int wno = (wave % WRN) * 64;
    int m0 = blockIdx.y * 128;
    int n0 = blockIdx.x * TN;

    float4v acc[MT][4];
    #pragma unroll
    for (int i = 0; i < MT; i++)
        #pragma unroll
        for (int j = 0; j < 4; j++)
            acc[i][j] = (float4v){0.f, 0.f, 0.f, 0.f};

    for (int k0 = 0; k0 < K; k0 += 32) {
        #pragma unroll
        for (int i = 0; i < 2; i++) {
            int idx = tid + i * 256;
            int r = idx >> 2, sg = idx & 3;
            *(short8*)&As[r][sg * 8] =
                *(const short8*)(A + (size_t)(m0 + r) * lda + k0 + sg * 8);
        }
        #pragma unroll
        for (int i = 0; i < TN / 64; i++) {
            int idx = tid + i * 256;
            int r = idx >> 2, sg = idx & 3;
            *(short8*)&Bs[r][sg * 8] =
                *(const short8*)(Bw + (size_t)(n0 + r) * ldb + k0 + sg * 8);
        }
        __syncthreads();
        short8 av[MT], bv[4];
        #pragma unroll
        for (int i = 0; i < MT; i++)
            av[i] = *(const short8*)&As[wmo + i * 16 + (lane & 15)][(lane >> 4) * 8];
        #pragma unroll
        for (int j = 0; j < 4; j++)
            bv[j] = *(const short8*)&Bs[wno + j * 16 + (lane & 15)][(lane >> 4) * 8];
        #pragma unroll
        for (int i = 0; i < MT; i++)
            #pragma unroll
            for (int j = 0; j < 4; j++)
                acc[i][j] = __builtin_amdgcn_mfma_f32_16x16x32_bf16(
                    av[i], bv[j], acc[i][j], 0, 0, 0);
        __syncthreads();
    }

    #pragma unroll
    for (int i = 0; i < MT; i++) {
        int rbase = m0 + wmo + i * 16 + (lane >> 4) * 4;
        #pragma unroll
        for (int j = 0; j < 4; j++) {
            int col = n0 + wno + j * 16 + (lane & 15);
            #pragma unroll
            for (int r = 0; r < 4; r++) {
                float v = acc[i][j][r];
                if (C)  C[(size_t)(rbase + r) * ldc + col] = v;
                if (Cb) Cb[(size_t)(rbase + r) * ldcb + col] = f2b(v);
            }
        }
    }
}

// ---------------------------------------------------------------------------
// Depthwise causal conv (width 4) + bias + SiLU. bf16 in/out.
// ---------------------------------------------------------------------------
__global__ __launch_bounds__(256) void k_conv_silu(const ushort* __restrict__ xz,
                                                   const float* __restrict__ cw,
                                                   const float* __restrict__ cb,
                                                   ushort* __restrict__ xa) {
    int gid = blockIdx.x * 256 + threadIdx.x;           // over NBL*384
    int d  = gid % DINNER;
    int bl = gid / DINNER;
    int l  = bl & (LL - 1);
    int b  = bl >> 12;
    float acc = cb[d];
    #pragma unroll
    for (int k = 0; k < DCONV; k++) {
        int ls = l - 3 + k;
        if (ls >= 0)
            acc += cw[d * DCONV + k] * b2f(xz[((size_t)(b * LL + ls)) * 768 + d]);
    }
    float sg = 1.f / (1.f + __expf(-acc));
    xa[gid] = f2b(acc * sg);
}

// ---------------------------------------------------------------------------
// x_proj as MFMA GEMM: M=32768, N=32 (20 real + 12 zero), K=384.
// Writes fp32 xdb32 (scan B/C source) and bf16 xdb16 (dt-GEMM A operand).
// Pad cols 20..31 come out zero (zero weights) -> safe K=32 in dt-GEMM.
// ---------------------------------------------------------------------------
__global__ __launch_bounds__(256) void k_xproj_mfma(const ushort* __restrict__ xa,
                                                    const ushort* __restrict__ xpwb,
                                                    float* __restrict__ xdb32,
                                                    ushort* __restrict__ xdb16) {
    __shared__ ushort As[128][40];
    __shared__ ushort Bs[32][40];
    int tid  = threadIdx.x;
    int lane = tid & 63;
    int wave = tid >> 6;
    int m0 = blockIdx.x * 128;
    float4v acc[2][2];
    #pragma unroll
    for (int i = 0; i < 2; i++)
        #pragma unroll
        for (int j = 0; j < 2; j++)
            acc[i][j] = (float4v){0.f, 0.f, 0.f, 0.f};
    for (int k0 = 0; k0 < 384; k0 += 32) {
        #pragma unroll
        for (int i = 0; i < 2; i++) {
            int idx = tid + i * 256;
            int r = idx >> 2, sg = idx & 3;
            *(short8*)&As[r][sg * 8] =
                *(const short8*)(xa + (size_t)(m0 + r) * 384 + k0 + sg * 8);
        }
        if (tid < 128) {
            int r = tid >> 2, sg = tid & 3;
            *(short8*)&Bs[r][sg * 8] =
                *(const short8*)(xpwb + (size_t)r * 384 + k0 + sg * 8);
        }
        __syncthreads();
        short8 av[2], bv[2];
        #pragma unroll
        for (int i = 0; i < 2; i++)
            av[i] = *(const short8*)&As[wave * 32 + i * 16 + (lane & 15)][(lane >> 4) * 8];
        #pragma unroll
        for (int j = 0; j < 2; j++)
            bv[j] = *(const short8*)&Bs[j * 16 + (lane & 15)][(lane >> 4) * 8];
        #pragma unroll
        for (int i = 0; i < 2; i++)
            #pragma unroll
            for (int j = 0; j < 2; j++)
                acc[i][j] = __builtin_amdgcn_mfma_f32_16x16x32_bf16(
                    av[i], bv[j], acc[i][j], 0, 0, 0);
        __syncthreads();
    }
    #pragma unroll
    for (int i = 0; i < 2; i++) {
        int rbase = m0 + wave * 32 + i * 16 + (lane >> 4) * 4;
        #pragma unroll
        for (int j = 0; j < 2; j++) {
            int col = j * 16 + (lane & 15);
            #pragma unroll
            for (int r = 0; r < 4; r++) {
                float v = acc[i][j][r];
                xdb32[(size_t)(rbase + r) * 32 + col] = v;
                xdb16[(size_t)(rbase + r) * 32 + col] = f2b(v);
            }
        }
    }
}

// ---------------------------------------------------------------------------
// dt GEMM + softplus: dtv[m,n] = softplus(sum_r xdbl[m,r]*dtw[n,r] + dtb[n]).
// K=32 (cols 12..31 hit zero weights). Wave = 16 rows x 384 cols (24 tiles).
// ---------------------------------------------------------------------------
__global__ __launch_bounds__(256) void k_dtgemm(const ushort* __restrict__ xdb16,
                                                const ushort* __restrict__ dtwpad,
                                                const float* __restrict__ dtb,
                                                float* __restrict__ dtv) {
    int lane = threadIdx.x & 63;
    int wave = threadIdx.x >> 6;
    int m0 = blockIdx.x * 64 + wave * 16;
    int ak = (lane >> 4) * 8;
    short8 av = *(const short8*)(xdb16 + (size_t)(m0 + (lane & 15)) * 32 + ak);
    int rbase = m0 + (lane >> 4) * 4;
    #pragma unroll
    for (int j = 0; j < 24; j++) {
        int col = j * 16 + (lane & 15);
        short8 bv = *(const short8*)(dtwpad + (size_t)col * 32 + ak);
        float4v acc = (float4v){0.f, 0.f, 0.f, 0.f};
        acc = __builtin_amdgcn_mfma_f32_16x16x32_bf16(av, bv, acc, 0, 0, 0);
        float bias = dtb[col];
        #pragma unroll
        for (int r = 0; r < 4; r++) {
            float s = acc[r] + bias;
            float sp = fmaxf(s, 0.f) + log1pf(__expf(-fabsf(s)));
            dtv[(size_t)(rbase + r) * DINNER + col] = sp;
        }
    }
}

// ---------------------------------------------------------------------------
// Chunked scan pass 1: per-chunk local scan from h=0 (dt preloaded).
// ---------------------------------------------------------------------------
__global__ __launch_bounds__(384) void k_scan_local(const ushort* __restrict__ xa,
                                                    const float* __restrict__ xdb32,
                                                    const float* __restrict__ dtvb,
                                                    const float* __restrict__ A_log,
                                                    float* __restrict__ carryA,
                                                    float* __restrict__ carryH) {
    int d     = threadIdx.x;
    int chunk = blockIdx.x;
    int b     = blockIdx.y;
    __shared__ float rows[CLEN * 32];
    size_t rbase = ((size_t)b * LL + (size_t)chunk * CLEN) * 32;
    for (int i = d; i < CLEN * 32; i += 384) rows[i] = xdb32[rbase + i];
    float As[DSTATE];
    #pragma unroll
    for (int s = 0; s < DSTATE; s++) As[s] = -__expf(A_log[d * DSTATE + s]);
    __syncthreads();
    float h[DSTATE]  = {0.f, 0.f, 0.f, 0.f};
    float ap[DSTATE] = {1.f, 1.f, 1.f, 1.f};
    size_t mbase = (size_t)b * LL + (size_t)chunk * CLEN;
    for (int l = 0; l < CLEN; l++) {
        size_t m = mbase + l;
        float dtvv = dtvb[m * DINNER + d];
        float xav  = b2f(xa[m * DINNER + d]);
        float du   = dtvv * xav;
        const float* row = &rows[l * 32];
        #pragma unroll
        for (int s = 0; s < DSTATE; s++) {
            float da = __expf(dtvv * As[s]);
            h[s]  = da * h[s] + du * row[DTRANK + s];
            ap[s] *= da;
        }
    }
    size_t cb = ((size_t)(b * DINNER + d) * DSTATE) * NCHUNK + chunk;
    #pragma unroll
    for (int s = 0; s < DSTATE; s++) {
        carryA[cb + (size_t)s * NCHUNK] = ap[s];
        carryH[cb + (size_t)s * NCHUNK] = h[s];
    }
}

// ---------------------------------------------------------------------------
// Pass 2: wave scan over 128 chunks (lane holds 2 chunks).
// Compose (A1,B1)∘(A2,B2) = (A1*A2, A2*B1+B2). Writes incoming state.
// ---------------------------------------------------------------------------
__global__ __launch_bounds__(256) void k_scan_combine(const float* __restrict__ carryA,
                                                      float* __restrict__ carryH) {
    int lane  = threadIdx.x & 63;
    int chain = blockIdx.x * 4 + (threadIdx.x >> 6);
    size_t base = (size_t)chain * NCHUNK;
    float a0 = carryA[base + 2 * lane];
    float b0 = carryH[base + 2 * lane];
    float a1 = carryA[base + 2 * lane + 1];
    float b1 = carryH[base + 2 * lane + 1];
    float A  = a0 * a1;
    float Bv = a1 * b0 + b1;
    #pragma unroll
    for (int off = 1; off < 64; off <<= 1) {
        float Aj = __shfl_up(A, off, 64);
        float Bj = __shfl_up(Bv, off, 64);
        if (lane >= off) {
            Bv = A * Bj + Bv;
            A  = A * Aj;
        }
    }
    float PB = __shfl_up(Bv, 1, 64);
    if (lane == 0) PB = 0.f;
    carryH[base + 2 * lane]     = PB;
    carryH[base + 2 * lane + 1] = a0 * PB + b0;
}

// ---------------------------------------------------------------------------
// Pass 3: seeded rerun; y = h·C + xa*D, y *= silu(z); write bf16 y.
// ---------------------------------------------------------------------------
__global__ __launch_bounds__(384) void k_scan_final(const ushort* __restrict__ xa,
                                                    const ushort* __restrict__ xz,
                                                    const float* __restrict__ xdb32,
                                                    const float* __restrict__ dtvb,
                                                    const float* __restrict__ A_log,
                                                    const float* __restrict__ Dp,
                                                    const float* __restrict__ carryH,
                                                    ushort* __restrict__ y) {
    int d     = threadIdx.x;
    int chunk = blockIdx.x;
    int b     = blockIdx.y;
    __shared__ float rows[CLEN * 32];
    size_t rbase = ((size_t)b * LL + (size_t)chunk * CLEN) * 32;
    for (int i = d; i < CLEN * 32; i += 384) rows[i] = xdb32[rbase + i];
    float As[DSTATE];
    #pragma unroll
    for (int s = 0; s < DSTATE; s++) As[s] = -__expf(A_log[d * DSTATE + s]);
    float Dd = Dp[d];
    size_t cb = ((size_t)(b * DINNER + d) * DSTATE) * NCHUNK + chunk;
    float h[DSTATE];
    #pragma unroll
    for (int s = 0; s < DSTATE; s++) h[s] = carryH[cb + (size_t)s * NCHUNK];
    __syncthreads();
    size_t mbase = (size_t)b * LL + (size_t)chunk * CLEN;
    for (int l = 0; l < CLEN; l++) {
        size_t m = mbase + l;
        float dtvv = dtvb[m * DINNER + d];
        float xav  = b2f(xa[m * DINNER + d]);
        float du   = dtvv * xav;
        const float* row = &rows[l * 32];
        float yv = 0.f;
        #pragma unroll
        for (int s = 0; s < DSTATE; s++) {
            float da = __expf(dtvv * As[s]);
            h[s] = da * h[s] + du * row[DTRANK + s];
            yv  += h[s] * row[DTRANK + DSTATE + s];
        }
        yv += xav * Dd;
        float zv = b2f(xz[m * 768 + DINNER + d]);
        yv *= zv / (1.f + __expf(-zv));
        y[m * DINNER + d] = f2b(yv);
    }
}

// ---------------------------------------------------------------------------
// Tail: low-rank (U,V) + residual(x) + LayerNorm, LDS-tiled for coalesced
// (B,C,L) reads and writes. Block = 64 l's x 192 c.
// ---------------------------------------------------------------------------
__global__ __launch_bounds__(256) void k_tail(const ushort* __restrict__ h1b,
                                              const float* __restrict__ x,
                                              const float* __restrict__ U,
                                              const float* __restrict__ V,
                                              const float* __restrict__ g,
                                              const float* __restrict__ be,
                                              float* __restrict__ out) {
    __shared__ float tile[EMBED * 65];
    int tid  = threadIdx.x;
    int lane = tid & 63;
    int wave = tid >> 6;
    int b  = blockIdx.y;
    int l0 = blockIdx.x * 64;
    for (int i = tid; i < EMBED * 64; i += 256) {
        int c = i >> 6, l = i & 63;
        tile[c * 65 + l] = x[((size_t)(b * EMBED + c)) * LL + l0 + l];
    }
    __syncthreads();
    for (int t = 0; t < 16; t++) {
        int lloc = wave * 16 + t;
        size_t m = (size_t)b * LL + l0 + lloc;
        float hv[3];
        #pragma unroll
        for (int i = 0; i < 3; i++) hv[i] = b2f(h1b[m * EMBED + lane + 64 * i]);
        float r[RANK];
        #pragma unroll
        for (int j = 0; j < RANK; j++) {
            float p = 0.f;
            #pragma unroll
            for (int i = 0; i < 3; i++) p += hv[i] * U[j * EMBED + lane + 64 * i];
            #pragma unroll
            for (int off = 1; off < 64; off <<= 1) p += __shfl_xor(p, off);
            r[j] = p;
        }
        float u[3], s1 = 0.f, s2 = 0.f;
        #pragma unroll
        for (int i = 0; i < 3; i++) {
            int c = lane + 64 * i;
            float v = r[0] * V[c * 4 + 0] + r[1] * V[c * 4 + 1]
                    + r[2] * V[c * 4 + 2] + r[3] * V[c * 4 + 3];
            u[i] = v + tile[c * 65 + lloc];
            s1 += u[i];
            s2 += u[i] * u[i];
        }
        #pragma unroll
        for (int off = 1; off < 64; off <<= 1) {
            s1 += __shfl_xor(s1, off);
            s2 += __shfl_xor(s2, off);
        }
        float mean = s1 * (1.f / EMBED);
        float var  = s2 * (1.f / EMBED) - mean * mean;
        float inv  = rsqrtf(var + 1e-5f);
        #pragma unroll
        for (int i = 0; i < 3; i++) {
            int c = lane + 64 * i;
            tile[c * 65 + lloc] = (u[i] - mean) * inv * g[c] + be[c];
        }
    }
    __syncthreads();
    for (int i = tid; i < EMBED * 64; i += 256) {
        int c = i >> 6, l = i & 63;
        out[((size_t)(b * EMBED + c)) * LL + l0 + l] = tile[c * 65 + l];
    }
}

// ---------------------------------------------------------------------------
extern "C" void kernel_launch(void* const* d_in, const int* in_sizes, int n_in,
                              void* d_out, int out_size, void* d_ws, size_t ws_size,
                              hipStream_t stream) {
    const float* x          = (const float*)d_in[0];
    const float* in_proj_w  = (const float*)d_in[1];
    const float* conv_w     = (const float*)d_in[2];
    const float* conv_b     = (const float*)d_in[3];
    const float* x_proj_w   = (const float*)d_in[4];
    const float* dt_proj_w  = (const float*)d_in[5];
    const float* dt_proj_b  = (const float*)d_in[6];
    const float* A_log      = (const float*)d_in[7];
    const float* Dp         = (const float*)d_in[8];
    const float* out_proj_w = (const float*)d_in[9];
    const float* U_w        = (const float*)d_in[10];
    const float* V_w        = (const float*)d_in[11];
    const float* ln_g       = (const float*)d_in[12];
    const float* ln_b       = (const float*)d_in[13];
    float* out = (float*)d_out;

    // Workspace layout: 64 MiB of fp32, then bf16 buffers (~188 MiB total).
    float* ws    = (float*)d_ws;
    float* xdb32 = ws;                                     // NBL*32
    float* dtv   = xdb32 + (size_t)NBL * 32;               // NBL*384
    float* cA    = dtv   + (size_t)NBL * DINNER;           // 8*384*4*128
    float* cH    = cA    + (size_t)BB * DINNER * DSTATE * NCHUNK;
    ushort* xz16   = (ushort*)(cH + (size_t)BB * DINNER * DSTATE * NCHUNK);
    ushort* xa16   = xz16   + (size_t)NBL * 768;
    ushort* yb     = xa16   + (size_t)NBL * DINNER;
    ushort* h0b    = yb     + (size_t)NBL * DINNER;
    ushort* h1b    = h0b    + (size_t)NBL * EMBED;
    ushort* wi     = h1b    + (size_t)NBL * EMBED;         // 2*768*192
    ushort* wo     = wi     + (size_t)NMIX * 768 * EMBED;  // 2*192*384
    ushort* xpwb   = wo     + (size_t)NMIX * EMBED * DINNER; // 2*32*384
    ushort* dtwpad = xpwb   + (size_t)NMIX * 32 * 384;       // 2*384*32

    const int n_wi = NMIX * 768 * EMBED;
    const int n_wo = NMIX * EMBED * DINNER;
    k_cast<<<(n_wi + 255) / 256, 256, 0, stream>>>(in_proj_w, wi, n_wi);
    k_cast<<<(n_wo + 255) / 256, 256, 0, stream>>>(out_proj_w, wo, n_wo);
    k_pad_xpw<<<(NMIX * 32 * 384 + 255) / 256, 256, 0, stream>>>(x_proj_w, xpwb);
    k_pad_dtw<<<(NMIX * 384 * 32 + 255) / 256, 256, 0, stream>>>(dt_proj_w, dtwpad);

    k_transpose<<<dim3(LL / 32, EMBED / 32, BB), dim3(32, 8), 0, stream>>>(x, h0b);

    const ushort* hinb = h0b;
    for (int mix = 0; mix < NMIX; mix++) {
        const float* Alg = A_log + (size_t)mix * DINNER * DSTATE;

        // in_proj -> xz bf16 (NBL,768)
        k_gemm_bf16<128, 2><<<dim3(768 / 128, NBL / 128), 256, 0, stream>>>(
            hinb, EMBED, wi + (size_t)mix * 768 * EMBED, EMBED,
            (float*)nullptr, 0, xz16, 768, EMBED);
        // conv + silu -> xa bf16
        k_conv_silu<<<(NBL * DINNER) / 256, 256, 0, stream>>>(
            xz16, conv_w + mix * DINNER * DCONV, conv_b + mix * DINNER, xa16);
        // x_proj MFMA -> xdb32 fp32 + xdb16 bf16 (reuse yb as xdb16 scratch)
        ushort* xdb16 = yb;
        k_xproj_mfma<<<NBL / 128, 256, 0, stream>>>(
            xa16, xpwb + (size_t)mix * 32 * 384, xdb32, xdb16);
        // dt GEMM + softplus -> dtv fp32
        k_dtgemm<<<NBL / 64, 256, 0, stream>>>(
            xdb16, dtwpad + (size_t)mix * 384 * 32, dt_proj_b + mix * DINNER, dtv);
        // chunked scan
        k_scan_local<<<dim3(NCHUNK, BB), 384, 0, stream>>>(
            xa16, xdb32, dtv, Alg, cA, cH);
        k_scan_combine<<<(BB * DINNER * DSTATE) / 4, 256, 0, stream>>>(cA, cH);
        k_scan_final<<<dim3(NCHUNK, BB), 384, 0, stream>>>(
            xa16, xz16, xdb32, dtv, Alg, Dp + mix * DINNER, cH, yb);
        // out_proj -> h1b bf16 only
        k_gemm_bf16<64, 1><<<dim3(EMBED / 64, NBL / 128), 256, 0, stream>>>(
            yb, DINNER, wo + (size_t)mix * EMBED * DINNER, DINNER,
            (float*)nullptr, 0, h1b, EMBED, DINNER);
        hinb = h1b;
    }

    // tail: low-rank + residual + LayerNorm -> out (B,C,H,W)
    k_tail<<<dim3(LL / 64, BB), 256, 0, stream>>>(h1b, x, U_w, V_w, ln_g, ln_b, out);
}